// Round 1
// baseline (1233.080 us; speedup 1.0000x reference)
//
#include <hip/hip_runtime.h>
#include <math.h>

#define D_MODEL 1024
#define NHEAD   16
#define HDIM    64
#define SEQ     2048
#define BATCH   2
#define NROWS   (BATCH*SEQ)   // 4096
#define BK      32

// ---------------------------------------------------------------- gdiag
// gdiag[h,d] = sum_i A[h,i,d]^2 + exp(log_lambda[h])
__global__ void gdiag_kernel(const float* __restrict__ A,
                             const float* __restrict__ log_lambda,
                             float* __restrict__ gdiag) {
    int id = blockIdx.x * 256 + threadIdx.x;   // 0..1023
    if (id >= NHEAD * HDIM) return;
    int h = id >> 6, d = id & 63;
    float s = 0.f;
#pragma unroll
    for (int i = 0; i < 16; ++i) {
        float a = A[(h * 16 + i) * HDIM + d];
        s += a * a;
    }
    gdiag[id] = s + __expf(log_lambda[h]);
}

// ---------------------------------------------------------------- ksum
// ksum[b,h,d] = sum_t k[b,h,t,d]
__global__ void ksum_kernel(const float* __restrict__ k, float* __restrict__ ksum) {
    int bh = blockIdx.x;                 // 0..31
    int d = threadIdx.x & 63;
    int g = threadIdx.x >> 6;            // 0..3
    const float* kp = k + (size_t)bh * SEQ * HDIM;
    float s = 0.f;
    for (int t = g; t < SEQ; t += 4) s += kp[t * HDIM + d];
    __shared__ float red[4][64];
    red[g][d] = s;
    __syncthreads();
    if (g == 0) ksum[bh * HDIM + d] = (red[0][d] + red[1][d]) + (red[2][d] + red[3][d]);
}

// ---------------------------------------------------------------- NT GEMM
// C[n,m] = sum_k Am[n,k]*W[m,k] + bias[m].  128x128 tile, BK=32, 8x8 micro.
// blockIdx.z selects (W,bias,out) triple so QKV runs as one launch.
// qkv_mode=1: out is (b,h,t,hd); qkv_mode=0: out is row-major (n, D_MODEL).
__global__ __launch_bounds__(256, 2)
void gemm_nt_kernel(const float* __restrict__ Am,
                    const float* __restrict__ W0, const float* __restrict__ bia0, float* __restrict__ out0,
                    const float* __restrict__ W1, const float* __restrict__ bia1, float* __restrict__ out1,
                    const float* __restrict__ W2, const float* __restrict__ bia2, float* __restrict__ out2,
                    int qkv_mode) {
    const int z = blockIdx.z;
    const float* W    = (z == 0) ? W0  : (z == 1) ? W1  : W2;
    const float* bias = (z == 0) ? bia0 : (z == 1) ? bia1 : bia2;
    float* out        = (z == 0) ? out0 : (z == 1) ? out1 : out2;

    __shared__ __align__(16) float As[BK][132];
    __shared__ __align__(16) float Ws[BK][132];
    const int tid = threadIdx.x;
    const int rBase = blockIdx.y * 128;
    const int cBase = blockIdx.x * 128;
    const int tr = tid >> 4, tc = tid & 15;

    float acc[64];
#pragma unroll
    for (int i = 0; i < 64; ++i) acc[i] = 0.f;

    for (int kt = 0; kt < D_MODEL; kt += BK) {
#pragma unroll
        for (int s = 0; s < 4; ++s) {
            int f4  = s * 256 + tid;        // 0..1023
            int row = f4 >> 3;              // 128 rows, 8 float4 per row
            int k4  = (f4 & 7) * 4;
            float4 av = *(const float4*)&Am[(size_t)(rBase + row) * D_MODEL + kt + k4];
            As[k4 + 0][row] = av.x; As[k4 + 1][row] = av.y;
            As[k4 + 2][row] = av.z; As[k4 + 3][row] = av.w;
            float4 wv = *(const float4*)&W[(size_t)(cBase + row) * D_MODEL + kt + k4];
            Ws[k4 + 0][row] = wv.x; Ws[k4 + 1][row] = wv.y;
            Ws[k4 + 2][row] = wv.z; Ws[k4 + 3][row] = wv.w;
        }
        __syncthreads();
#pragma unroll 8
        for (int kk = 0; kk < BK; ++kk) {
            float4 a0 = *(const float4*)&As[kk][tr * 4];
            float4 a1 = *(const float4*)&As[kk][64 + tr * 4];
            float4 b0 = *(const float4*)&Ws[kk][tc * 4];
            float4 b1 = *(const float4*)&Ws[kk][64 + tc * 4];
            float a[8]  = {a0.x, a0.y, a0.z, a0.w, a1.x, a1.y, a1.z, a1.w};
            float bb[8] = {b0.x, b0.y, b0.z, b0.w, b1.x, b1.y, b1.z, b1.w};
#pragma unroll
            for (int ii = 0; ii < 8; ++ii)
#pragma unroll
                for (int jj = 0; jj < 8; ++jj)
                    acc[ii * 8 + jj] = fmaf(a[ii], bb[jj], acc[ii * 8 + jj]);
        }
        __syncthreads();
    }

#pragma unroll
    for (int ii = 0; ii < 8; ++ii) {
        int r = rBase + ((ii < 4) ? (tr * 4 + ii) : (64 + tr * 4 + (ii - 4)));
#pragma unroll
        for (int ch = 0; ch < 2; ++ch) {
            int c = cBase + ch * 64 + tc * 4;
            float4 v;
            v.x = acc[ii * 8 + ch * 4 + 0] + bias[c + 0];
            v.y = acc[ii * 8 + ch * 4 + 1] + bias[c + 1];
            v.z = acc[ii * 8 + ch * 4 + 2] + bias[c + 2];
            v.w = acc[ii * 8 + ch * 4 + 3] + bias[c + 3];
            if (qkv_mode) {
                int b = r >> 11, t = r & (SEQ - 1);
                int h = c >> 6, hd = c & 63;
                *(float4*)&out[(((size_t)(b * NHEAD + h) * SEQ + t) << 6) + hd] = v;
            } else {
                *(float4*)&out[(size_t)r * D_MODEL + c] = v;
            }
        }
    }
}

// ---------------------------------------------------------------- flash attention
// logits[t,j] = Sg[t,:].k[j,:],  Sg = (2048*q - ksum)*gdiag  (c-term cancels in softmax)
// Tiles: 64 q-rows x 64 k-cols. LDS: sgT[d][i], kT[d][j] (reused as p[i][j]), vs[j][d].
__global__ __launch_bounds__(256, 2)
void flash_kernel(const float* __restrict__ q, const float* __restrict__ kg,
                  const float* __restrict__ vg, const float* __restrict__ ksum,
                  const float* __restrict__ gdiag, float* __restrict__ o) {
    __shared__ __align__(16) float sgT[64][68];   // [d][i]
    __shared__ __align__(16) float kT[64][68];    // [d][j] for logits, then [i][j] holds p
    __shared__ __align__(16) float vs[64][68];    // [j][d]

    const int tid = threadIdx.x;
    const int t0 = blockIdx.x * 64;
    const int h = blockIdx.y;
    const int b = blockIdx.z;
    const size_t bh = (size_t)b * NHEAD + h;
    const float* qp  = q  + bh * SEQ * HDIM;
    const float* kp  = kg + bh * SEQ * HDIM;
    const float* vp  = vg + bh * SEQ * HDIM;
    const float* ksp = ksum + bh * HDIM;
    const float* gdp = gdiag + (size_t)h * HDIM;

    // build sgT (transposed): sgT[d][i] = (2048*q[t0+i,d] - ksum[d]) * gdiag[d]
#pragma unroll
    for (int s = 0; s < 4; ++s) {
        int f4  = s * 256 + tid;
        int row = f4 >> 4;
        int dc  = (f4 & 15) * 4;
        float4 qv = *(const float4*)&qp[(size_t)(t0 + row) * HDIM + dc];
        float4 kv = *(const float4*)&ksp[dc];
        float4 gv = *(const float4*)&gdp[dc];
        sgT[dc + 0][row] = (2048.f * qv.x - kv.x) * gv.x;
        sgT[dc + 1][row] = (2048.f * qv.y - kv.y) * gv.y;
        sgT[dc + 2][row] = (2048.f * qv.z - kv.z) * gv.z;
        sgT[dc + 3][row] = (2048.f * qv.w - kv.w) * gv.w;
    }

    const int tr = tid >> 4, tc = tid & 15;
    const int r0 = tr * 4;
    float m_i[4], l_i[4], oacc[16];
#pragma unroll
    for (int i = 0; i < 4; ++i) { m_i[i] = -INFINITY; l_i[i] = 0.f; }
#pragma unroll
    for (int i = 0; i < 16; ++i) oacc[i] = 0.f;

    for (int j0 = 0; j0 < SEQ; j0 += 64) {
        // stage k (transposed) and v tiles
#pragma unroll
        for (int s = 0; s < 4; ++s) {
            int f4  = s * 256 + tid;
            int row = f4 >> 4;
            int dc  = (f4 & 15) * 4;
            float4 kv = *(const float4*)&kp[(size_t)(j0 + row) * HDIM + dc];
            kT[dc + 0][row] = kv.x; kT[dc + 1][row] = kv.y;
            kT[dc + 2][row] = kv.z; kT[dc + 3][row] = kv.w;
            float4 vv = *(const float4*)&vp[(size_t)(j0 + row) * HDIM + dc];
            *(float4*)&vs[row][dc] = vv;
        }
        __syncthreads();   // #1: k,v staged

        // logits 4x4 micro-tile
        float lg[16];
#pragma unroll
        for (int i = 0; i < 16; ++i) lg[i] = 0.f;
#pragma unroll 4
        for (int d = 0; d < 64; ++d) {
            float4 a4 = *(const float4*)&sgT[d][r0];
            float4 b4 = *(const float4*)&kT[d][tc * 4];
            float a[4]  = {a4.x, a4.y, a4.z, a4.w};
            float bb[4] = {b4.x, b4.y, b4.z, b4.w};
#pragma unroll
            for (int ii = 0; ii < 4; ++ii)
#pragma unroll
                for (int jj = 0; jj < 4; ++jj)
                    lg[ii * 4 + jj] = fmaf(a[ii], bb[jj], lg[ii * 4 + jj]);
        }
        __syncthreads();   // #2: all logits read from kT; kT now free for p

        // online softmax update; write p into kT's space as p[i][j]
        float alpha[4];
#pragma unroll
        for (int ii = 0; ii < 4; ++ii) {
            float tmax = fmaxf(fmaxf(lg[ii * 4 + 0], lg[ii * 4 + 1]),
                               fmaxf(lg[ii * 4 + 2], lg[ii * 4 + 3]));
#pragma unroll
            for (int mask = 8; mask >= 1; mask >>= 1)
                tmax = fmaxf(tmax, __shfl_xor(tmax, mask, 16));
            float mn = fmaxf(m_i[ii], tmax);
            alpha[ii] = __expf(m_i[ii] - mn);
            m_i[ii] = mn;
            float p0 = __expf(lg[ii * 4 + 0] - mn);
            float p1 = __expf(lg[ii * 4 + 1] - mn);
            float p2 = __expf(lg[ii * 4 + 2] - mn);
            float p3 = __expf(lg[ii * 4 + 3] - mn);
            *(float4*)&kT[r0 + ii][tc * 4] = make_float4(p0, p1, p2, p3);
            float psum = (p0 + p1) + (p2 + p3);
#pragma unroll
            for (int mask = 8; mask >= 1; mask >>= 1)
                psum += __shfl_xor(psum, mask, 16);
            l_i[ii] = l_i[ii] * alpha[ii] + psum;
        }
        __syncthreads();   // #3: p ready

        // rescale o, accumulate PV: thread owns rows r0..r0+3, dims tc*4..+3
#pragma unroll
        for (int ii = 0; ii < 4; ++ii)
#pragma unroll
            for (int dd = 0; dd < 4; ++dd)
                oacc[ii * 4 + dd] *= alpha[ii];
#pragma unroll 4
        for (int j = 0; j < 64; ++j) {
            float4 vv = *(const float4*)&vs[j][tc * 4];
            float va[4] = {vv.x, vv.y, vv.z, vv.w};
            float p[4];
#pragma unroll
            for (int ii = 0; ii < 4; ++ii) p[ii] = kT[r0 + ii][j];
#pragma unroll
            for (int ii = 0; ii < 4; ++ii)
#pragma unroll
                for (int dd = 0; dd < 4; ++dd)
                    oacc[ii * 4 + dd] = fmaf(p[ii], va[dd], oacc[ii * 4 + dd]);
        }
        __syncthreads();   // #4: vs and p consumed, safe to restage
    }

    // normalize and store to o_ws in (b, t, h*64+hd) layout
#pragma unroll
    for (int ii = 0; ii < 4; ++ii) {
        float inv = 1.f / l_i[ii];
        int t = t0 + r0 + ii;
        float4 ov;
        ov.x = oacc[ii * 4 + 0] * inv; ov.y = oacc[ii * 4 + 1] * inv;
        ov.z = oacc[ii * 4 + 2] * inv; ov.w = oacc[ii * 4 + 3] * inv;
        *(float4*)&o[((size_t)b * SEQ + t) * D_MODEL + h * HDIM + tc * 4] = ov;
    }
}

// ---------------------------------------------------------------- launcher
extern "C" void kernel_launch(void* const* d_in, const int* in_sizes, int n_in,
                              void* d_out, int out_size, void* d_ws, size_t ws_size,
                              hipStream_t stream) {
    const float* x  = (const float*)d_in[0];
    const float* Wq = (const float*)d_in[1];
    const float* bq = (const float*)d_in[2];
    const float* Wk = (const float*)d_in[3];
    const float* bk = (const float*)d_in[4];
    const float* Wv = (const float*)d_in[5];
    const float* bv = (const float*)d_in[6];
    const float* Wo = (const float*)d_in[7];
    const float* bo = (const float*)d_in[8];
    const float* A  = (const float*)d_in[9];
    const float* ll = (const float*)d_in[10];
    float* out = (float*)d_out;

    float* ws = (float*)d_ws;
    const size_t QKV = (size_t)BATCH * NHEAD * SEQ * HDIM;   // 4,194,304 floats
    float* q_ws    = ws;
    float* k_ws    = ws + QKV;
    float* v_ws    = ws + 2 * QKV;
    float* o_ws    = ws + 3 * QKV;
    float* gd_ws   = ws + 4 * QKV;              // 1024 floats
    float* ksum_ws = gd_ws + NHEAD * HDIM;      // 2048 floats
    // total ws use: ~67.1 MB

    gdiag_kernel<<<4, 256, 0, stream>>>(A, ll, gd_ws);

    dim3 gqkv(D_MODEL / 128, NROWS / 128, 3);   // 8 x 32 x 3 = 768 blocks
    gemm_nt_kernel<<<gqkv, 256, 0, stream>>>(x,
                                             Wq, bq, q_ws,
                                             Wk, bk, k_ws,
                                             Wv, bv, v_ws,
                                             1);

    ksum_kernel<<<BATCH * NHEAD, 256, 0, stream>>>(k_ws, ksum_ws);

    flash_kernel<<<dim3(SEQ / 64, NHEAD, BATCH), 256, 0, stream>>>(
        q_ws, k_ws, v_ws, ksum_ws, gd_ws, o_ws);

    dim3 gout(D_MODEL / 128, NROWS / 128, 1);   // 256 blocks
    gemm_nt_kernel<<<gout, 256, 0, stream>>>(o_ws,
                                             Wo, bo, out,
                                             Wo, bo, out,
                                             Wo, bo, out,
                                             0);
}

// Round 2
// 397.699 us; speedup vs baseline: 3.1005x; 3.1005x over previous
//
#include <hip/hip_runtime.h>
#include <math.h>

#define D_MODEL 1024
#define NHEAD   16
#define HDIM    64
#define SEQ     2048
#define BATCH   2
#define NROWS   (BATCH*SEQ)   // 4096

typedef unsigned short u16;
typedef __attribute__((ext_vector_type(4))) unsigned short u16x4;
typedef __attribute__((ext_vector_type(8))) short short8;
typedef __attribute__((ext_vector_type(4))) float f32x4;

// ---- bf16 helpers (RNE) ----
__device__ __forceinline__ u16 f2bf(float x) {
    unsigned int u = __float_as_uint(x);
    u += 0x7fffu + ((u >> 16) & 1u);
    return (u16)(u >> 16);
}
__device__ __forceinline__ float bf2f(u16 h) {
    return __uint_as_float(((unsigned int)h) << 16);
}
// 8-bf16 LDS access via 2x b64 (rows are 8B-aligned, not 16B)
__device__ __forceinline__ short8 ld8(const u16* p) {
    u16x4 a = *(const u16x4*)p;
    u16x4 b = *(const u16x4*)(p + 4);
    short8 r;
    r[0]=(short)a[0]; r[1]=(short)a[1]; r[2]=(short)a[2]; r[3]=(short)a[3];
    r[4]=(short)b[0]; r[5]=(short)b[1]; r[6]=(short)b[2]; r[7]=(short)b[3];
    return r;
}
__device__ __forceinline__ void st8(u16* p, short8 v) {
    u16x4 a, b;
    a[0]=(u16)v[0]; a[1]=(u16)v[1]; a[2]=(u16)v[2]; a[3]=(u16)v[3];
    b[0]=(u16)v[4]; b[1]=(u16)v[5]; b[2]=(u16)v[6]; b[3]=(u16)v[7];
    *(u16x4*)p = a; *(u16x4*)(p + 4) = b;
}

// ---------------------------------------------------------------- gdiag
// gdiag[h,d] = (sum_i A[h,i,d]^2 + exp(log_lambda[h])) * log2(e)   (log2-domain softmax)
__global__ void gdiag_kernel(const float* __restrict__ A,
                             const float* __restrict__ log_lambda,
                             float* __restrict__ gdiag) {
    int id = blockIdx.x * 256 + threadIdx.x;
    if (id >= NHEAD * HDIM) return;
    int h = id >> 6, d = id & 63;
    float s = 0.f;
#pragma unroll
    for (int i = 0; i < 16; ++i) {
        float a = A[(h * 16 + i) * HDIM + d];
        s += a * a;
    }
    gdiag[id] = (s + __expf(log_lambda[h])) * 1.4426950408889634f;
}

// ---------------------------------------------------------------- prep: fp32 -> bf16 hi/lo
__global__ void prep_split(const float* __restrict__ x,
                           const float* __restrict__ Wq, const float* __restrict__ Wk,
                           const float* __restrict__ Wv, const float* __restrict__ Wo,
                           u16* __restrict__ xh, u16* __restrict__ xl,
                           u16* __restrict__ wqh, u16* __restrict__ wql,
                           u16* __restrict__ wkh, u16* __restrict__ wkl,
                           u16* __restrict__ wvh, u16* __restrict__ woh) {
    int seg = blockIdx.y;
    int i = blockIdx.x * 256 + threadIdx.x;   // float4 index
    const float* src; u16* dh; u16* dl; int n4;
    if      (seg == 0) { src = x;  dh = xh;  dl = xl;      n4 = NROWS * D_MODEL / 4; }
    else if (seg == 1) { src = Wq; dh = wqh; dl = wql;     n4 = D_MODEL * D_MODEL / 4; }
    else if (seg == 2) { src = Wk; dh = wkh; dl = wkl;     n4 = D_MODEL * D_MODEL / 4; }
    else if (seg == 3) { src = Wv; dh = wvh; dl = nullptr; n4 = D_MODEL * D_MODEL / 4; }
    else               { src = Wo; dh = woh; dl = nullptr; n4 = D_MODEL * D_MODEL / 4; }
    if (i >= n4) return;
    float4 v = *(const float4*)&src[(size_t)i * 4];
    float vv[4] = {v.x, v.y, v.z, v.w};
    u16x4 hv, lv;
#pragma unroll
    for (int j = 0; j < 4; ++j) {
        u16 hb = f2bf(vv[j]);
        hv[j] = hb;
        lv[j] = f2bf(vv[j] - bf2f(hb));
    }
    *(u16x4*)&dh[(size_t)i * 4] = hv;
    if (dl) *(u16x4*)&dl[(size_t)i * 4] = lv;
}

// ---------------------------------------------------------------- MFMA NT GEMM
// out[r][c] = sum_k A[r][k]*W[c][k] + bias[c]; A,W in bf16 hi(/lo), fp32 acc.
// NP3: 3-pass split (ah*bh + ah*bl + al*bh); else 1-pass plain bf16.
// 128x128 tile, BK=32, 4 waves, each wave = 32 rows x 128 cols (2x8 mfma frags).
template<int NP3>
__global__ __launch_bounds__(256)
void gemm_mfma(const u16* __restrict__ Ah, const u16* __restrict__ Al,
               const u16* __restrict__ BhA, const u16* __restrict__ BlA, const float* __restrict__ biasA,
               float* outfA, u16* auxhA, u16* auxlA, float* ksumA,
               const u16* __restrict__ BhB, const u16* __restrict__ BlB, const float* __restrict__ biasB,
               float* outfB, u16* auxhB, u16* auxlB, float* ksumB,
               int out_layout) {
    const int z = blockIdx.z;
    const u16* Bh = (z == 0) ? BhA : BhB;
    const u16* Bl = (z == 0) ? BlA : BlB;
    const float* bias = (z == 0) ? biasA : biasB;
    float* outf = (z == 0) ? outfA : outfB;
    u16* auxh   = (z == 0) ? auxhA : auxhB;
    u16* auxl   = (z == 0) ? auxlA : auxlB;
    float* ksump= (z == 0) ? ksumA : ksumB;

    __shared__ u16 As_h[128][36], Bs_h[128][36];
    __shared__ u16 As_l[128][36], Bs_l[128][36];

    const int tid = threadIdx.x;
    const int w = tid >> 6, lane = tid & 63, quad = lane >> 4, n16 = lane & 15;
    const int rBase = blockIdx.y * 128;
    const int cBase = blockIdx.x * 128;

    f32x4 acc[2][8] = {};

    for (int kt = 0; kt < D_MODEL; kt += 32) {
#pragma unroll
        for (int s = 0; s < 2; ++s) {
            int id = s * 256 + tid;          // 512 chunks of 8 bf16
            int row = id >> 2;
            int c8 = (id & 3) * 8;
            st8(&As_h[row][c8], *(const short8*)&Ah[(size_t)(rBase + row) * D_MODEL + kt + c8]);
            st8(&Bs_h[row][c8], *(const short8*)&Bh[(size_t)(cBase + row) * D_MODEL + kt + c8]);
            if (NP3) {
                st8(&As_l[row][c8], *(const short8*)&Al[(size_t)(rBase + row) * D_MODEL + kt + c8]);
                st8(&Bs_l[row][c8], *(const short8*)&Bl[(size_t)(cBase + row) * D_MODEL + kt + c8]);
            }
        }
        __syncthreads();

        short8 a_h[2], a_l[2];
#pragma unroll
        for (int mt = 0; mt < 2; ++mt) {
            a_h[mt] = ld8(&As_h[w * 32 + mt * 16 + n16][quad * 8]);
            if (NP3) a_l[mt] = ld8(&As_l[w * 32 + mt * 16 + n16][quad * 8]);
        }
#pragma unroll
        for (int nt = 0; nt < 8; ++nt) {
            short8 b_h = ld8(&Bs_h[nt * 16 + n16][quad * 8]);
            short8 b_l;
            if (NP3) b_l = ld8(&Bs_l[nt * 16 + n16][quad * 8]);
#pragma unroll
            for (int mt = 0; mt < 2; ++mt) {
                acc[mt][nt] = __builtin_amdgcn_mfma_f32_16x16x32_bf16(a_h[mt], b_h, acc[mt][nt], 0, 0, 0);
                if (NP3) {
                    acc[mt][nt] = __builtin_amdgcn_mfma_f32_16x16x32_bf16(a_h[mt], b_l, acc[mt][nt], 0, 0, 0);
                    acc[mt][nt] = __builtin_amdgcn_mfma_f32_16x16x32_bf16(a_l[mt], b_h, acc[mt][nt], 0, 0, 0);
                }
            }
        }
        __syncthreads();
    }

    // epilogue: C row = quad*4+reg (within 16x16 tile), col = n16
    float csum[8];
#pragma unroll
    for (int nt = 0; nt < 8; ++nt) csum[nt] = 0.f;
#pragma unroll
    for (int mt = 0; mt < 2; ++mt) {
#pragma unroll
        for (int nt = 0; nt < 8; ++nt) {
            int c = cBase + nt * 16 + n16;
            float bc = bias[c];
            int rb = rBase + w * 32 + mt * 16 + quad * 4;
#pragma unroll
            for (int reg = 0; reg < 4; ++reg) {
                float val = acc[mt][nt][reg] + bc;
                int rr = rb + reg;
                size_t idx = out_layout
                    ? ((size_t)(((rr >> 11) * NHEAD + (c >> 6)) * SEQ + (rr & (SEQ - 1)))) * HDIM + (c & 63)
                    : (size_t)rr * D_MODEL + c;
                if (outf) outf[idx] = val;
                if (auxh) {
                    u16 hb = f2bf(val);
                    auxh[idx] = hb;
                    if (auxl) auxl[idx] = f2bf(val - bf2f(hb));
                }
                csum[nt] += val;
            }
        }
    }
    if (ksump) {
#pragma unroll
        for (int nt = 0; nt < 8; ++nt) {
            float cs = csum[nt];
            cs += __shfl_xor(cs, 16);
            cs += __shfl_xor(cs, 32);
            if (quad == 0) {
                int c = cBase + nt * 16 + n16;
                int bb = rBase >> 11;
                atomicAdd(&ksump[(bb * NHEAD + (c >> 6)) * HDIM + (c & 63)], cs);
            }
        }
    }
}

// ---------------------------------------------------------------- v transpose: (b,h,t,hd) bf16 -> (b,h,hd,t) bf16
__global__ __launch_bounds__(256)
void vtrans_kernel(const u16* __restrict__ vh, u16* __restrict__ vT) {
    __shared__ u16 tile[64][72];
    const int tid = threadIdx.x;
    const int t0 = blockIdx.x * 64;
    const int bh = blockIdx.y;
    const u16* vp = vh + (size_t)bh * SEQ * HDIM;
#pragma unroll
    for (int s = 0; s < 2; ++s) {
        int id = s * 256 + tid;
        int row = id >> 3, c8 = (id & 7) * 8;
        st8(&tile[row][c8], *(const short8*)&vp[(size_t)(t0 + row) * HDIM + c8]);
    }
    __syncthreads();
#pragma unroll
    for (int s = 0; s < 2; ++s) {
        int id = s * 256 + tid;
        int d = id >> 3, t8 = (id & 7) * 8;
        short8 r;
#pragma unroll
        for (int i = 0; i < 8; ++i) r[i] = (short)tile[t8 + i][d];
        *(short8*)&vT[((size_t)bh * HDIM + d) * SEQ + t0 + t8] = r;
    }
}

// ---------------------------------------------------------------- flash attention (MFMA, split-bf16 logits)
// logits(log2) = Sg . k, Sg = (2048*q - ksum) * gdiag  (gdiag pre-scaled by log2 e)
__global__ __launch_bounds__(256)
void flash_mfma(const float* __restrict__ q, const u16* __restrict__ kh,
                const u16* __restrict__ kl, const u16* __restrict__ vT,
                const float* __restrict__ ksum, const float* __restrict__ gdiag,
                u16* __restrict__ o) {
    __shared__ u16 khs[64][68], kls[64][68], vTs[64][68];
    __shared__ u16 ps[4][16][68];

    const int tid = threadIdx.x;
    const int w = tid >> 6, lane = tid & 63, quad = lane >> 4, n16 = lane & 15;
    const int t0 = blockIdx.x * 64;
    const int h = blockIdx.y, b = blockIdx.z;
    const size_t bh = (size_t)b * NHEAD + h;
    const float* qp = q + bh * SEQ * HDIM;
    const u16* khp = kh + bh * SEQ * HDIM;
    const u16* klp = kl + bh * SEQ * HDIM;
    const u16* vtp = vT + bh * HDIM * SEQ;

    // Sg A-fragments in registers: A[m=n16][k=quad*8+j (+32*kc)]
    short8 sgh[2], sgl[2];
    {
        int qrow = t0 + w * 16 + n16;
#pragma unroll
        for (int kc = 0; kc < 2; ++kc) {
            int d0 = kc * 32 + quad * 8;
            float4 q0 = *(const float4*)&qp[(size_t)qrow * HDIM + d0];
            float4 q1 = *(const float4*)&qp[(size_t)qrow * HDIM + d0 + 4];
            float4 k0 = *(const float4*)&ksum[bh * HDIM + d0];
            float4 k1 = *(const float4*)&ksum[bh * HDIM + d0 + 4];
            float4 g0 = *(const float4*)&gdiag[(size_t)h * HDIM + d0];
            float4 g1 = *(const float4*)&gdiag[(size_t)h * HDIM + d0 + 4];
            float sg[8];
            sg[0] = (2048.f * q0.x - k0.x) * g0.x; sg[1] = (2048.f * q0.y - k0.y) * g0.y;
            sg[2] = (2048.f * q0.z - k0.z) * g0.z; sg[3] = (2048.f * q0.w - k0.w) * g0.w;
            sg[4] = (2048.f * q1.x - k1.x) * g1.x; sg[5] = (2048.f * q1.y - k1.y) * g1.y;
            sg[6] = (2048.f * q1.z - k1.z) * g1.z; sg[7] = (2048.f * q1.w - k1.w) * g1.w;
#pragma unroll
            for (int j = 0; j < 8; ++j) {
                u16 hb = f2bf(sg[j]);
                sgh[kc][j] = (short)hb;
                sgl[kc][j] = (short)f2bf(sg[j] - bf2f(hb));
            }
        }
    }

    f32x4 oaccv[4] = {};
    float m_i[4], l_i[4];
#pragma unroll
    for (int r = 0; r < 4; ++r) { m_i[r] = -INFINITY; l_i[r] = 0.f; }

    for (int j0 = 0; j0 < SEQ; j0 += 64) {
        // stage k_hi, k_lo, vT tiles
#pragma unroll
        for (int s = 0; s < 2; ++s) {
            int id = s * 256 + tid;
            int row = id >> 3, c8 = (id & 7) * 8;
            st8(&khs[row][c8], *(const short8*)&khp[(size_t)(j0 + row) * HDIM + c8]);
            st8(&kls[row][c8], *(const short8*)&klp[(size_t)(j0 + row) * HDIM + c8]);
            st8(&vTs[row][c8], *(const short8*)&vtp[(size_t)row * SEQ + j0 + c8]);
        }
        __syncthreads();

        // QK^T: 3-pass split-bf16. lg[nt] covers cols 16nt, rows quad*4+reg.
        f32x4 lg[4] = {};
#pragma unroll
        for (int kc = 0; kc < 2; ++kc) {
#pragma unroll
            for (int nt = 0; nt < 4; ++nt) {
                short8 b_h = ld8(&khs[nt * 16 + n16][kc * 32 + quad * 8]);
                short8 b_l = ld8(&kls[nt * 16 + n16][kc * 32 + quad * 8]);
                lg[nt] = __builtin_amdgcn_mfma_f32_16x16x32_bf16(sgh[kc], b_h, lg[nt], 0, 0, 0);
                lg[nt] = __builtin_amdgcn_mfma_f32_16x16x32_bf16(sgh[kc], b_l, lg[nt], 0, 0, 0);
                lg[nt] = __builtin_amdgcn_mfma_f32_16x16x32_bf16(sgl[kc], b_h, lg[nt], 0, 0, 0);
            }
        }

        // online softmax (log2 domain); row r' = quad*4+r handled by the quad's 16 lanes
        float alpha[4];
#pragma unroll
        for (int r = 0; r < 4; ++r) {
            float mx = fmaxf(fmaxf(lg[0][r], lg[1][r]), fmaxf(lg[2][r], lg[3][r]));
            mx = fmaxf(mx, __shfl_xor(mx, 1));
            mx = fmaxf(mx, __shfl_xor(mx, 2));
            mx = fmaxf(mx, __shfl_xor(mx, 4));
            mx = fmaxf(mx, __shfl_xor(mx, 8));
            float mn = fmaxf(m_i[r], mx);
            alpha[r] = exp2f(m_i[r] - mn);
            m_i[r] = mn;
            float p0 = exp2f(lg[0][r] - mn);
            float p1 = exp2f(lg[1][r] - mn);
            float p2 = exp2f(lg[2][r] - mn);
            float p3 = exp2f(lg[3][r] - mn);
            int prow = quad * 4 + r;
            ps[w][prow][ 0 + n16] = f2bf(p0);
            ps[w][prow][16 + n16] = f2bf(p1);
            ps[w][prow][32 + n16] = f2bf(p2);
            ps[w][prow][48 + n16] = f2bf(p3);
            float psum = (p0 + p1) + (p2 + p3);
            psum += __shfl_xor(psum, 1);
            psum += __shfl_xor(psum, 2);
            psum += __shfl_xor(psum, 4);
            psum += __shfl_xor(psum, 8);
            l_i[r] = l_i[r] * alpha[r] + psum;
        }
#pragma unroll
        for (int nt = 0; nt < 4; ++nt)
#pragma unroll
            for (int r = 0; r < 4; ++r) oaccv[nt][r] *= alpha[r];

        // PV: A = p (per-wave LDS), B = vT. Same-wave ds write->read (DS pipe is in-order).
        short8 pa0 = ld8(&ps[w][n16][quad * 8]);
        short8 pa1 = ld8(&ps[w][n16][32 + quad * 8]);
#pragma unroll
        for (int nt = 0; nt < 4; ++nt) {
            short8 v0 = ld8(&vTs[nt * 16 + n16][quad * 8]);
            short8 v1 = ld8(&vTs[nt * 16 + n16][32 + quad * 8]);
            oaccv[nt] = __builtin_amdgcn_mfma_f32_16x16x32_bf16(pa0, v0, oaccv[nt], 0, 0, 0);
            oaccv[nt] = __builtin_amdgcn_mfma_f32_16x16x32_bf16(pa1, v1, oaccv[nt], 0, 0, 0);
        }
        __syncthreads();
    }

    // epilogue: write o_hi bf16, row-major (b, t, h*64+d)
#pragma unroll
    for (int r = 0; r < 4; ++r) {
        float inv = 1.f / l_i[r];
        int t = t0 + w * 16 + quad * 4 + r;
#pragma unroll
        for (int nt = 0; nt < 4; ++nt) {
            int d = nt * 16 + n16;
            o[((size_t)(b * SEQ + t)) * D_MODEL + h * HDIM + d] = f2bf(oaccv[nt][r] * inv);
        }
    }
}

// ---------------------------------------------------------------- launcher
extern "C" void kernel_launch(void* const* d_in, const int* in_sizes, int n_in,
                              void* d_out, int out_size, void* d_ws, size_t ws_size,
                              hipStream_t stream) {
    const float* x  = (const float*)d_in[0];
    const float* Wq = (const float*)d_in[1];
    const float* bq = (const float*)d_in[2];
    const float* Wk = (const float*)d_in[3];
    const float* bk = (const float*)d_in[4];
    const float* Wv = (const float*)d_in[5];
    const float* bv = (const float*)d_in[6];
    const float* Wo = (const float*)d_in[7];
    const float* bo = (const float*)d_in[8];
    const float* A  = (const float*)d_in[9];
    const float* ll = (const float*)d_in[10];
    float* out = (float*)d_out;

    const size_t NQKV = (size_t)NROWS * D_MODEL;   // 4,194,304
    const size_t NW = (size_t)D_MODEL * D_MODEL;   // 1,048,576
    char* base = (char*)d_ws;
    float* q_ws = (float*)base;            base += NQKV * 4;
    u16* xh  = (u16*)base;                 base += NQKV * 2;   // reused as o_hi after QKV
    u16* xl  = (u16*)base;                 base += NQKV * 2;   // reused as vT after QKV
    u16* khw = (u16*)base;                 base += NQKV * 2;
    u16* klw = (u16*)base;                 base += NQKV * 2;
    u16* vhw = (u16*)base;                 base += NQKV * 2;
    u16* wqh = (u16*)base;                 base += NW * 2;
    u16* wql = (u16*)base;                 base += NW * 2;
    u16* wkh = (u16*)base;                 base += NW * 2;
    u16* wkl = (u16*)base;                 base += NW * 2;
    u16* wvh = (u16*)base;                 base += NW * 2;
    u16* woh = (u16*)base;                 base += NW * 2;
    float* gd_ws   = (float*)base;         base += NHEAD * HDIM * 4;
    float* ksum_ws = (float*)base;         base += BATCH * NHEAD * HDIM * 4;

    hipMemsetAsync(ksum_ws, 0, BATCH * NHEAD * HDIM * sizeof(float), stream);

    prep_split<<<dim3(4096, 5), 256, 0, stream>>>(x, Wq, Wk, Wv, Wo,
                                                  xh, xl, wqh, wql, wkh, wkl, wvh, woh);
    gdiag_kernel<<<4, 256, 0, stream>>>(A, ll, gd_ws);

    // Q (z=0) + K (z=1): 3-pass split-bf16; K writes k_hi/k_lo + ksum atomics
    gemm_mfma<1><<<dim3(8, 32, 2), 256, 0, stream>>>(
        xh, xl,
        wqh, wql, bq, q_ws, nullptr, nullptr, nullptr,
        wkh, wkl, bk, nullptr, khw, klw, ksum_ws,
        1);
    // V: 1-pass bf16, writes v_hi bf16 only
    gemm_mfma<0><<<dim3(8, 32, 1), 256, 0, stream>>>(
        xh, nullptr,
        wvh, nullptr, bv, nullptr, vhw, nullptr, nullptr,
        wvh, nullptr, bv, nullptr, vhw, nullptr, nullptr,
        1);

    u16* vTw = xl;   // alias: x_lo dead after QKV GEMMs
    u16* ohw = xh;   // alias: x_hi dead after QKV GEMMs
    vtrans_kernel<<<dim3(SEQ / 64, BATCH * NHEAD), 256, 0, stream>>>(vhw, vTw);

    flash_mfma<<<dim3(SEQ / 64, NHEAD, BATCH), 256, 0, stream>>>(
        q_ws, khw, klw, vTw, ksum_ws, gd_ws, ohw);

    // out-proj: 1-pass bf16, row-major fp32 output
    gemm_mfma<0><<<dim3(8, 32, 1), 256, 0, stream>>>(
        ohw, nullptr,
        woh, nullptr, bo, out, nullptr, nullptr, nullptr,
        woh, nullptr, bo, out, nullptr, nullptr, nullptr,
        0);
}